// Round 3
// baseline (2952.445 us; speedup 1.0000x reference)
//
#include <hip/hip_runtime.h>

typedef unsigned short u16;
typedef short short8 __attribute__((ext_vector_type(8)));
typedef float f32x4 __attribute__((ext_vector_type(4)));
typedef unsigned short u16x4 __attribute__((ext_vector_type(4)));

#define B_  256
#define T_  600
#define TC_ 75    // time chunk (8 chunks)
#define HID 200
#define G4  800
#define HSTR 232  // hbuf row stride (u16): 464B -> 2-way bank aliasing only (free)
#define WCOLS 224 // padded whh row length (u16) so kt6 is a normal 32-K fragment

__device__ __forceinline__ float bf2f(u16 u) {
  union { unsigned int i; float f; } v; v.i = ((unsigned int)u) << 16; return v.f;
}
__device__ __forceinline__ u16 f2bf(float f) {
  union { float f; unsigned int i; } v; v.f = f;
  unsigned int r = v.i + 0x7FFFu + ((v.i >> 16) & 1u);
  return (u16)(r >> 16);
}
__device__ __forceinline__ float sigm(float x) {
  float e = __expf(-x);
  return __builtin_amdgcn_rcpf(1.f + e);
}

// single per-step barrier: LDS writes must be visible; global ops stay in flight
#define BARRIER_LGKM() asm volatile("s_waitcnt lgkmcnt(0)\n\ts_barrier" ::: "memory")

// ---------------------------------------------------------------------------
// Pad / permute / downcast f32 weights into aligned bf16 scratch.
// ---------------------------------------------------------------------------
__global__ __launch_bounds__(256) void padperm_k(const float* __restrict__ src,
                                                 u16* __restrict__ dst,
                                                 int rows, int srows, int scols,
                                                 int dcols, int perm) {
  int idx = blockIdx.x * 256 + threadIdx.x;
  if (idx >= rows * dcols) return;
  int r = idx / dcols, c = idx - r * dcols;
  int sr = perm ? ((r & 3) * 200 + (r >> 2)) : r;
  dst[idx] = (r < srows && c < scols) ? f2bf(src[(size_t)sr * scols + c]) : (u16)0;
}

// ---------------------------------------------------------------------------
// Transpose chunk: x [B][129][600] f32 -> xTq [B][TC_][160] bf16, window t0.
// ---------------------------------------------------------------------------
__global__ __launch_bounds__(256) void transpose_k(const float* __restrict__ x,
                                                   u16* __restrict__ xTq, int t0) {
  __shared__ u16 tile[129 * 65];
  const int b = blockIdx.y;
  const int tt0 = blockIdx.x * 64;
  const int tid = threadIdx.x;
  for (int idx = tid; idx < 129 * 64; idx += 256) {
    int i = idx >> 6, tt = idx & 63;
    int t = t0 + tt0 + tt;
    tile[i * 65 + tt] = (tt0 + tt < TC_ && t < T_)
        ? f2bf(x[((size_t)b * 129 + i) * T_ + t]) : (u16)0;
  }
  __syncthreads();
  for (int idx = tid; idx < 64 * 160; idx += 256) {
    int tt = idx / 160, i = idx - tt * 160;
    if (tt0 + tt < TC_)
      xTq[((size_t)b * TC_ + tt0 + tt) * 160 + i] = (i < 129) ? tile[i * 65 + tt] : (u16)0;
  }
}

// ---------------------------------------------------------------------------
// 256-thread GEMM: out = ACT(A @ W^T + bias). Used for gemm2 / fc1 / fc2.
// ---------------------------------------------------------------------------
template<int ASRC, int LDK, int NSRC, int NSTORE, int BPERM, int ACT, int OUTM, int CHUNK>
__global__ __launch_bounds__(256, 2) void gemm_k(
    const u16* __restrict__ A, const u16* __restrict__ W,
    const float* __restrict__ B1, const float* __restrict__ B2,
    void* __restrict__ outv, int ldout, int t0) {
  constexpr int NCH = LDK / 8;
  constexpr int KT = LDK / 32;
  __shared__ u16 la[128 * LDK];
  __shared__ float lbias[128];
  const int tid = threadIdx.x;
  const int mb = blockIdx.x, nb = blockIdx.y;

  for (int idx = tid; idx < 128 * NCH; idx += 256) {
    int row = idx / NCH, c = idx - row * NCH;
    int m = mb * 128 + row;
    size_t arow;
    if (CHUNK) {
      int b = m / TC_;
      int tt = m - b * TC_;
      arow = (size_t)b * T_ + t0 + tt;
    } else {
      arow = (size_t)m;
    }
    short8 v = (short8)0;
    if (8 * c + 8 <= ASRC)
      v = *(const short8*)(A + arow * ASRC + 8 * c);
    *(short8*)(la + row * LDK + 8 * c) = v;
  }
  if (tid < 128) {
    int p = nb * 128 + tid;
    float bv = 0.f;
    if (p < NSRC) {
      int orig = BPERM ? ((p & 3) * 200 + (p >> 2)) : p;
      bv = B1[orig];
      if (BPERM) bv += B2[orig];
    }
    lbias[tid] = bv;
  }
  __syncthreads();

  const int w = tid >> 6, l = tid & 63;
  const int quad = l >> 4, l15 = l & 15;
  const int mq = (w >> 1) * 64, nq = (w & 1) * 64;

  const u16* wrow[4];
#pragma unroll
  for (int nt = 0; nt < 4; ++nt) {
    int p = nb * 128 + nq + nt * 16 + l15;
    wrow[nt] = W + (size_t)((p < NSRC) ? p : 0) * LDK;
  }

  f32x4 acc[4][4];
#pragma unroll
  for (int i = 0; i < 4; ++i)
#pragma unroll
    for (int j = 0; j < 4; ++j) acc[i][j] = (f32x4)0.f;

#pragma unroll
  for (int kt = 0; kt < KT; ++kt) {
    const int k0 = kt * 32 + quad * 8;
    short8 bf[4];
#pragma unroll
    for (int nt = 0; nt < 4; ++nt) bf[nt] = *(const short8*)(wrow[nt] + k0);
    short8 af[4];
#pragma unroll
    for (int mt = 0; mt < 4; ++mt)
      af[mt] = *(const short8*)(la + (mq + mt * 16 + l15) * LDK + k0);
#pragma unroll
    for (int mt = 0; mt < 4; ++mt)
#pragma unroll
      for (int nt = 0; nt < 4; ++nt)
        acc[mt][nt] = __builtin_amdgcn_mfma_f32_16x16x32_bf16(af[mt], bf[nt],
                                                              acc[mt][nt], 0, 0, 0);
  }

#pragma unroll
  for (int mt = 0; mt < 4; ++mt) {
#pragma unroll
    for (int nt = 0; nt < 4; ++nt) {
#pragma unroll
      for (int r = 0; r < 4; ++r) {
        int rowl = mq + mt * 16 + quad * 4 + r;
        int coln = nq + nt * 16 + l15;
        int pg = nb * 128 + coln;
        if (pg < NSTORE) {
          float v = (pg < NSRC) ? (acc[mt][nt][r] + lbias[coln]) : 0.f;
          if (ACT == 1) v = fmaxf(v, 0.f);
          if (ACT == 2) v = sigm(v);
          size_t m = (size_t)mb * 128 + rowl;
          if (OUTM == 0) {
            ((u16*)outv)[m * (size_t)ldout + pg] = f2bf(v);
          } else {
            int b = (int)(m / T_);
            int t = (int)(m - (size_t)b * T_);
            ((float*)outv)[((size_t)b * 129 + pg) * T_ + t] = v;
          }
        }
      }
    }
  }
}

// ---------------------------------------------------------------------------
// Persistent LSTM recurrence body. 16 waves; 3 register-weight slots per wave
// (tiles w+16s, kt0..6 fully register-resident; whh rows padded to WCOLS=224
// so kt6 is a normal zero-padded 32-K fragment). Tiles 48,49 handled by waves
// 0,1 as a 4th slot with LDS-resident weights. hbuf double-buffered: ONE
// barrier per step (reads are register-consumed before each wave's barrier
// arrival, so next-step writes to the other buffer cannot race).
// ---------------------------------------------------------------------------
__device__ __forceinline__ void rec_body(const u16* __restrict__ xg,
                                         const u16* __restrict__ whh,
                                         u16* __restrict__ houtb, int hb_stride,
                                         const u16* __restrict__ hprevb, int hp_bstride,
                                         float* __restrict__ cst, int has_prev,
                                         int blk, char* smem) {
  u16* hb  = (u16*)smem;                 // [2][16*HSTR] = 14848 B
  u16* wx  = (u16*)(smem + 14848);       // [2][7][512]  = 14336 B

  const int tid = threadIdx.x;
  const int w = tid >> 6, l = tid & 63;
  const int quad = l >> 4, l15 = l & 15;
  const int b0 = blk * 16;

  // ---- prologue: weights ----
  short8 wreg[3][7];
#pragma unroll
  for (int s = 0; s < 3; ++s) {
    int p = (w + 16 * s) * 16 + l15;
    int orig = (p & 3) * 200 + (p >> 2);
    const u16* wb = whh + (size_t)orig * WCOLS;
#pragma unroll
    for (int kk = 0; kk < 7; ++kk)
      wreg[s][kk] = *(const short8*)(wb + kk * 32 + quad * 8);
  }
  if (w < 2) {  // stage overflow tiles 48,49 into LDS
    int p = (48 + w) * 16 + l15;
    int orig = (p & 3) * 200 + (p >> 2);
    const u16* wb = whh + (size_t)orig * WCOLS;
#pragma unroll
    for (int kk = 0; kk < 7; ++kk)
      *(short8*)(wx + (w * 7 + kk) * 512 + l * 8) = *(const short8*)(wb + kk * 32 + quad * 8);
  }
  // zero pad cols 200..231 of both h buffers (real cols are fully published)
  { int bsel = tid >> 9, r = (tid >> 5) & 15, cc = tid & 31;
    hb[bsel * (16 * HSTR) + r * HSTR + 200 + cc] = 0; }

  // ---- state ----
  float c[4]; u16 hreg[4];
#pragma unroll
  for (int s = 0; s < 4; ++s) { c[s] = 0.f; hreg[s] = 0; }
  float* cstp = cst + (size_t)(b0 + l15) * HID;
  if (has_prev) {
#pragma unroll
    for (int s = 0; s < 3; ++s) {
      int unit = (w + 16 * s) * 4 + quad;
      hreg[s] = hprevb[(size_t)(b0 + l15) * hp_bstride + unit];
      c[s] = cstp[unit];
    }
    if (w < 2) {
      int unit = 192 + 4 * w + quad;
      hreg[3] = hprevb[(size_t)(b0 + l15) * hp_bstride + unit];
      c[3] = cstp[unit];
    }
  }

  // xg gather base + first prefetch
  const u16* xptr = xg + (size_t)(b0 + l15) * TC_ * G4 + w * 16 + quad * 4;
  u16x4 xv[4];
#pragma unroll
  for (int s = 0; s < 3; ++s) xv[s] = *(const u16x4*)(xptr + s * 256);
  xv[3] = (w < 2) ? *(const u16x4*)(xptr + 768) : (u16x4)0;

  u16* hout = houtb + (size_t)(b0 + l15) * hb_stride;

  // publish h(-1) into buffer 0
#pragma unroll
  for (int s = 0; s < 3; ++s)
    hb[l15 * HSTR + (w + 16 * s) * 4 + quad] = hreg[s];
  if (w < 2)
    hb[l15 * HSTR + 192 + 4 * w + quad] = hreg[3];

  __syncthreads();  // prologue fence (weights, pad zeros, h(-1) visible)

  for (int t = 0; t < TC_; ++t) {
    const u16* hr = hb + (t & 1) * (16 * HSTR);
    u16* hw = hb + ((t + 1) & 1) * (16 * HSTR);

    f32x4 acc[4];
#pragma unroll
    for (int s = 0; s < 4; ++s) acc[s] = (f32x4)0.f;

#pragma unroll
    for (int kk = 0; kk < 7; ++kk) {  // kk=6 -> offset 192 (== 6*32), zero-padded
      short8 hf = *(const short8*)(hr + l15 * HSTR + kk * 32 + quad * 8);
      acc[0] = __builtin_amdgcn_mfma_f32_16x16x32_bf16(wreg[0][kk], hf, acc[0], 0, 0, 0);
      acc[1] = __builtin_amdgcn_mfma_f32_16x16x32_bf16(wreg[1][kk], hf, acc[1], 0, 0, 0);
      acc[2] = __builtin_amdgcn_mfma_f32_16x16x32_bf16(wreg[2][kk], hf, acc[2], 0, 0, 0);
      if (w < 2) {
        short8 wz = *(const short8*)(wx + (w * 7 + kk) * 512 + l * 8);
        acc[3] = __builtin_amdgcn_mfma_f32_16x16x32_bf16(wz, hf, acc[3], 0, 0, 0);
      }
    }

    // ---- lane-local cell update ----
#pragma unroll
    for (int s = 0; s < 4; ++s) {
      if (s == 3 && w >= 2) break;
      float vi = acc[s][0] + bf2f(xv[s][0]);
      float vf = acc[s][1] + bf2f(xv[s][1]);
      float vg = acc[s][2] + bf2f(xv[s][2]);
      float vo = acc[s][3] + bf2f(xv[s][3]);
      float iv = sigm(vi);
      float fv = sigm(vf);
      float gv = 2.f * sigm(2.f * vg) - 1.f;  // tanh
      float ov = sigm(vo);
      float cn = fv * c[s] + iv * gv;
      c[s] = cn;
      float th = 2.f * sigm(2.f * cn) - 1.f;
      hreg[s] = f2bf(ov * th);
    }

    // publish h(t) into the other buffer
#pragma unroll
    for (int s = 0; s < 3; ++s)
      hw[l15 * HSTR + (w + 16 * s) * 4 + quad] = hreg[s];
    if (w < 2)
      hw[l15 * HSTR + 192 + 4 * w + quad] = hreg[3];

    // global h(t) store (stays in flight; vmcnt never drained in-loop)
#pragma unroll
    for (int s = 0; s < 3; ++s)
      hout[(size_t)t * HID + (w + 16 * s) * 4 + quad] = hreg[s];
    if (w < 2)
      hout[(size_t)t * HID + 192 + 4 * w + quad] = hreg[3];

    // prefetch xg(t+1)
    if (t + 1 < TC_) {
      const u16* xp = xptr + (size_t)(t + 1) * G4;
#pragma unroll
      for (int s = 0; s < 3; ++s) xv[s] = *(const u16x4*)(xp + s * 256);
      if (w < 2) xv[3] = *(const u16x4*)(xp + 768);
    }
    BARRIER_LGKM();  // single per-step barrier
  }

  // carry state
#pragma unroll
  for (int s = 0; s < 3; ++s) cstp[(w + 16 * s) * 4 + quad] = c[s];
  if (w < 2) cstp[192 + 4 * w + quad] = c[3];
}

// ---------------------------------------------------------------------------
// 1024-thread GEMM body for layer-1 input GEMM (xTq @ wp1^T + bias -> xg).
// 128 rows x 512 cols per block; 16 waves = 2 m-quads x 8 n-quads of 64x64.
// ---------------------------------------------------------------------------
__device__ __forceinline__ void gemm1_body(const u16* __restrict__ A,
                                           const u16* __restrict__ W,
                                           const float* __restrict__ B1,
                                           const float* __restrict__ B2,
                                           u16* __restrict__ out, int bb,
                                           char* smem) {
  u16* la = (u16*)smem;                    // [128][160] = 40960 B
  float* lbias = (float*)(smem + 40960);   // [512]      =  2048 B
  const int tid = threadIdx.x;
  const int mb = bb >> 1, nb = bb & 1;

  for (int idx = tid; idx < 128 * 20; idx += 1024) {
    int row = idx / 20, cc = idx - row * 20;
    *(short8*)(la + row * 160 + 8 * cc) =
        *(const short8*)(A + (size_t)(mb * 128 + row) * 160 + 8 * cc);
  }
  if (tid < 512) {
    int p = nb * 512 + tid;
    float bv = 0.f;
    if (p < 800) { int orig = (p & 3) * 200 + (p >> 2); bv = B1[orig] + B2[orig]; }
    lbias[tid] = bv;
  }
  __syncthreads();

  const int w = tid >> 6, l = tid & 63;
  const int quad = l >> 4, l15 = l & 15;
  const int mq = (w >> 3) * 64, nq = (w & 7) * 64;

  const u16* wrow[4];
#pragma unroll
  for (int nt = 0; nt < 4; ++nt) {
    int p = nb * 512 + nq + nt * 16 + l15;
    wrow[nt] = W + (size_t)((p < 800) ? p : 0) * 160;
  }

  f32x4 acc[4][4];
#pragma unroll
  for (int i = 0; i < 4; ++i)
#pragma unroll
    for (int j = 0; j < 4; ++j) acc[i][j] = (f32x4)0.f;

#pragma unroll
  for (int kt = 0; kt < 5; ++kt) {
    const int k0 = kt * 32 + quad * 8;
    short8 bf[4];
#pragma unroll
    for (int nt = 0; nt < 4; ++nt) bf[nt] = *(const short8*)(wrow[nt] + k0);
    short8 af[4];
#pragma unroll
    for (int mt = 0; mt < 4; ++mt)
      af[mt] = *(const short8*)(la + (mq + mt * 16 + l15) * 160 + k0);
#pragma unroll
    for (int mt = 0; mt < 4; ++mt)
#pragma unroll
      for (int nt = 0; nt < 4; ++nt)
        acc[mt][nt] = __builtin_amdgcn_mfma_f32_16x16x32_bf16(af[mt], bf[nt],
                                                              acc[mt][nt], 0, 0, 0);
  }

#pragma unroll
  for (int mt = 0; mt < 4; ++mt) {
#pragma unroll
    for (int nt = 0; nt < 4; ++nt) {
#pragma unroll
      for (int r = 0; r < 4; ++r) {
        int rowl = mq + mt * 16 + quad * 4 + r;
        int coln = nq + nt * 16 + l15;
        int pg = nb * 512 + coln;
        if (pg < 800) {
          float v = acc[mt][nt][r] + lbias[coln];
          out[(size_t)(mb * 128 + rowl) * 800 + pg] = f2bf(v);
        }
      }
    }
  }
}

// ---------------------------------------------------------------------------
// Fused launch: blocks [0,nA) rec layer-1 chunk, [nA,nA+nB) rec layer-2
// chunk, rest run the (independent) layer-1 input GEMM for the next chunk.
// ---------------------------------------------------------------------------
__global__ __launch_bounds__(1024) void fused_k(
    const u16* __restrict__ xgA, const u16* __restrict__ whhA,
    u16* __restrict__ hA, int hsA, const u16* __restrict__ hpA, int hpsA,
    float* __restrict__ cstA, int prevA,
    const u16* __restrict__ xgB, const u16* __restrict__ whhB,
    u16* __restrict__ hB, int hsB, const u16* __restrict__ hpB, int hpsB,
    float* __restrict__ cstB, int prevB,
    const u16* __restrict__ gA, const u16* __restrict__ gW,
    const float* __restrict__ gB1, const float* __restrict__ gB2,
    u16* __restrict__ gOut,
    int nA, int nB, int nG) {
  __shared__ __align__(16) char smem[43008];
  int bb = blockIdx.x;
  if (bb < nA) { rec_body(xgA, whhA, hA, hsA, hpA, hpsA, cstA, prevA, bb, smem); return; }
  bb -= nA;
  if (bb < nB) { rec_body(xgB, whhB, hB, hsB, hpB, hpsB, cstB, prevB, bb, smem); return; }
  bb -= nB;
  if (bb < nG) gemm1_body(gA, gW, gB1, gB2, gOut, bb, smem);
}

// ---------------------------------------------------------------------------
extern "C" void kernel_launch(void* const* d_in, const int* in_sizes, int n_in,
                              void* d_out, int out_size, void* d_ws, size_t ws_size,
                              hipStream_t stream) {
  (void)in_sizes; (void)n_in; (void)out_size; (void)ws_size;
  const float* x     = (const float*)d_in[0];
  const float* w_ih1 = (const float*)d_in[1];
  const float* w_hh1 = (const float*)d_in[2];
  const float* b_ih1 = (const float*)d_in[3];
  const float* b_hh1 = (const float*)d_in[4];
  const float* w_ih2 = (const float*)d_in[5];
  const float* w_hh2 = (const float*)d_in[6];
  const float* b_ih2 = (const float*)d_in[7];
  const float* b_hh2 = (const float*)d_in[8];
  const float* fc1_w = (const float*)d_in[9];
  const float* fc1_b = (const float*)d_in[10];
  const float* fc2_w = (const float*)d_in[11];
  const float* fc2_b = (const float*)d_in[12];
  float* out = (float*)d_out;

  // workspace layout (bytes, 16-aligned); total ~176.9 MB
  char* ws = (char*)d_ws;
  u16*   xg0   = (u16*)(ws);                     //  30,720,000  [256][75][800]
  u16*   xg1   = (u16*)(ws + 30720000LL);        //  30,720,000
  u16*   xgB   = (u16*)(ws + 61440000LL);        //  30,720,000
  u16*   h2    = (u16*)(ws + 92160000LL);        //  61,440,000  [256][600][200]
  u16*   h1c0  = (u16*)(ws + 153600000LL);       //   7,680,000  [256][75][200]
  u16*   h1c1  = (u16*)(ws + 161280000LL);       //   7,680,000
  u16*   xTq   = (u16*)(ws + 168960000LL);       //   6,144,000  [256][75][160]
  float* cst1  = (float*)(ws + 175104000LL);     //     204,800  [256][200] f32
  float* cst2  = (float*)(ws + 175308800LL);     //     204,800
  u16*   wp1   = (u16*)(ws + 175513600LL);       //     256,000  [800][160]
  u16*   wp2   = (u16*)(ws + 175769600LL);       //     358,400  [800][224]
  u16*   fc1p  = (u16*)(ws + 176128000LL);       //      57,792  [129][224]
  u16*   fc2p  = (u16*)(ws + 176185792LL);       //      41,280  [129][160]
  u16*   whh1c = (u16*)(ws + 176227072LL);       //     358,400  [800][224]
  u16*   whh2c = (u16*)(ws + 176585472LL);       //     358,400
  u16*   y1    = (u16*)(ws);                     // reuse xg0/xg1 after pipeline

  u16* xgp[2] = {xg0, xg1};
  u16* h1c[2] = {h1c0, h1c1};

  padperm_k<<<(800 * 160 + 255) / 256, 256, 0, stream>>>(w_ih1, wp1, 800, 800, 129, 160, 1);
  padperm_k<<<(800 * 224 + 255) / 256, 256, 0, stream>>>(w_ih2, wp2, 800, 800, 200, 224, 1);
  padperm_k<<<(129 * 224 + 255) / 256, 256, 0, stream>>>(fc1_w, fc1p, 129, 129, 200, 224, 0);
  padperm_k<<<(129 * 160 + 255) / 256, 256, 0, stream>>>(fc2_w, fc2p, 129, 129, 129, 160, 0);
  padperm_k<<<(800 * 224 + 255) / 256, 256, 0, stream>>>(w_hh1, whh1c, 800, 800, 200, 224, 0);
  padperm_k<<<(800 * 224 + 255) / 256, 256, 0, stream>>>(w_hh2, whh2c, 800, 800, 200, 224, 0);

  // chunk 0 input GEMM (gemm-only fused launch)
  transpose_k<<<dim3(2, 256), 256, 0, stream>>>(x, xTq, 0);
  fused_k<<<dim3(300), 1024, 0, stream>>>(
      xg0, whh1c, h1c0, 15000, h1c0, 15000, cst1, 0,
      xgB, whh2c, h2, 120000, h2, 120000, cst2, 0,
      xTq, wp1, b_ih1, b_hh1, xg0,
      0, 0, 300);

  // software pipeline: stage i runs rec1(chunk i) || rec2(chunk i-1) || gemm1(chunk i+1)
  for (int i = 0; i <= 8; ++i) {
    if (i < 7)
      transpose_k<<<dim3(2, 256), 256, 0, stream>>>(x, xTq, (i + 1) * TC_);
    const int nA = (i < 8) ? 16 : 0;
    const int nB = (i >= 1) ? 16 : 0;
    const int nG = (i < 7) ? 300 : 0;
    const int ib = (i >= 1) ? (i - 1) : 0;  // layer-2 chunk index
    fused_k<<<dim3(nA + nB + nG), 1024, 0, stream>>>(
        /*A: layer-1 chunk i*/
        xgp[i & 1], whh1c, h1c[i & 1], 15000,
        (i >= 1) ? (h1c[(i - 1) & 1] + 74 * HID) : h1c[0], 15000, cst1, (i >= 1) ? 1 : 0,
        /*B: layer-2 chunk i-1*/
        xgB, whh2c, h2 + (size_t)ib * 75 * HID, 120000,
        (ib >= 1) ? (h2 + ((size_t)ib * 75 - 1) * HID) : h2, 120000, cst2, (ib >= 1) ? 1 : 0,
        /*G: layer-1 input GEMM chunk i+1*/
        xTq, wp1, b_ih1, b_hh1, xgp[(i + 1) & 1],
        nA, nB, nG);
    if (i < 8)  // layer-2 input GEMM for chunk i (consumed by next fused launch)
      gemm_k<200, 224, 800, 800, 1, 0, 0, 0>
          <<<dim3(150, 7), 256, 0, stream>>>(h1c[i & 1], wp2, b_ih2, b_hh2, xgB, 800, 0);
  }

  // y1 = relu(h2 @ fc1^T + b)
  gemm_k<200, 224, 129, 144, 0, 1, 0, 0>
      <<<dim3(1200, 2), 256, 0, stream>>>(h2, fc1p, fc1_b, fc1_b, y1, 144, 0);
  // out = sigmoid(y1 @ fc2^T + b), f32 scatter to [B][129][T]
  gemm_k<144, 160, 129, 129, 0, 2, 1, 0>
      <<<dim3(1200, 2), 256, 0, stream>>>(y1, fc2p, fc2_b, fc2_b, out, 0, 0);
}